// Round 15
// baseline (400.813 us; speedup 1.0000x reference)
//
#include <hip/hip_runtime.h>
#include <hip/hip_bf16.h>
#include <hip/hip_fp16.h>

// Storage-dtype-templated load: DT=0 bf16, DT=1 fp16, DT=2 f32.
template <int DT>
__device__ __forceinline__ float ldT(const void* p, long i) {
  if (DT == 0) {
    unsigned int a = ((unsigned int)((const unsigned short*)p)[i]) << 16;
    union { unsigned int u; float f; } c; c.u = a; return c.f;
  } else if (DT == 1) {
    return __half2float(((const __half*)p)[i]);
  } else {
    return ((const float*)p)[i];
  }
}
template <int DT>
__device__ __forceinline__ bool msknzT(const void* p, long i) {
  if (DT < 2) return ((const unsigned short*)p)[i] != 0;  // 0.0 encodes as 0x0000
  return ((const float*)p)[i] != 0.f;
}
__device__ __forceinline__ float wred64(float v) {
#pragma unroll
  for (int off = 1; off < 64; off <<= 1) v += __shfl_xor(v, off, 64);
  return v;
}
__device__ __forceinline__ void ct67_itab(int bi, int& i, int& t) {
  const int toff[8] = {0, 1536, 4608, 6144, 9216, 10752, 13824, 15360};
  i = 0;
  while (bi >= toff[i + 1]) i++;
  t = bi - toff[i];
}
template <int DT>
__device__ __forceinline__ void ct67_mask(int i, const void* adj00, const void* b01,
                                          const void* adj11, const void* b12,
                                          const void* adj22, const void*& mp,
                                          long& mts, long& mss) {
  switch (i) {
    case 0: mp = adj00; mts = 1536; mss = 1; break;
    case 1: mp = b01;   mts = 1;    mss = 3072; break;
    case 2: mp = b01;   mts = 3072; mss = 1; break;
    case 3: mp = adj11; mts = 3072; mss = 1; break;
    case 4: mp = b12;   mts = 1;    mss = 1536; break;
    case 5: mp = b12;   mts = 1536; mss = 1; break;
    default: mp = adj22; mts = 1536; mss = 1; break;
  }
}
// per-block self-init of ranges (24 threads) — replaces the init kernel
__device__ __forceinline__ void ct67_selfranges(const int* b0, const int* b1, const int* b2,
                                                int* sR, int tid) {
  if (tid < 24) {
    int d = tid / 8, b = tid % 8;
    const int* bel = (d == 0) ? b0 : ((d == 1) ? b1 : b2);
    int N = (d == 1) ? 3072 : 1536;
    int lo = 0, hi = N;
    while (lo < hi) { int m = (lo + hi) / 2; if (bel[m] < b) lo = m + 1; else hi = m; }
    int st = lo; hi = N;
    while (lo < hi) { int m = (lo + hi) / 2; if (bel[m] < b + 1) lo = m + 1; else hi = m; }
    sR[tid * 2] = st;
    sR[tid * 2 + 1] = lo;
  }
}
__device__ __forceinline__ int ct67_selfdt(const unsigned short* x0u) {
  float vals[32], mean = 0.f, var = 0.f;
  for (int i = 0; i < 32; i++) {
    union { unsigned int u; float f; } c;
    c.u = ((unsigned int)x0u[i]) << 16;
    vals[i] = c.f; mean += c.f;
  }
  mean /= 32.f;
  for (int i = 0; i < 32; i++) var += (vals[i] - mean) * (vals[i] - mean);
  var /= 32.f;
  return (var < 1e-6f) ? 1 : ((var < 1e3f) ? 0 : 2);
}

// ---------------- merged ELL-build + embed + self-init (one launch) -------------
// blocks [0,3840): ELL build, 4 waves x 1 row. blocks [3840,5376): embed 4 rows.
template <int DT>
__device__ void ellem_body(const void* adj00, const void* b01, const void* adj11,
                           const void* b12, const void* adj22,
                           const int* bel0, const int* bel1, const int* bel2,
                           const int* sR, int* ell, int* nnz, int ellok,
                           const void* x0, const void* pe0, const void* wf0,
                           const void* bf0, const void* wp0, const void* x1,
                           const void* pe1, const void* wf1, const void* bf1,
                           const void* wp1, const void* x2, const void* pe2,
                           const void* wf2, const void* bf2, const void* wp2,
                           float* hout) {
  int tid = threadIdx.x;
  int lane = tid % 64, wid = tid / 64;
  if (blockIdx.x < 3840) {
    if (!ellok) return;
    const int sdv[7] = {0, 0, 1, 1, 1, 2, 2};
    const int tdv[7] = {0, 1, 0, 1, 2, 1, 2};
    int bi = blockIdx.x * 4 + wid;
    int i, t;
    ct67_itab(bi, i, t);
    const void* mp; long mts, mss;
    ct67_mask<DT>(i, adj00, b01, adj11, b12, adj22, mp, mts, mss);
    const int* belt = (tdv[i] == 0) ? bel0 : ((tdv[i] == 1) ? bel1 : bel2);
    int b = belt[t];
    if (b < 0) b = 0;
    if (b > 7) b = 7;
    int s0 = sR[(sdv[i] * 8 + b) * 2], s1 = sR[(sdv[i] * 8 + b) * 2 + 1];
    int base = 0;
    int* dst = ell + (long)bi * 128;
    auto append = [&](bool pred, int val) {
      unsigned long long bal = __ballot(pred);
      int pos = __popcll(bal & ((1ull << lane) - 1ull));
      if (pred && base + pos < 128) dst[base + pos] = val;
      base += __popcll(bal);
    };
    if (DT < 2 && mss == 1) {
      // vectorized contiguous scan (hit order within row is unordered — softmax invariant)
      const unsigned short* mrow = (const unsigned short*)mp + (long)t * mts;
      int sA4 = (s0 + 3) & ~3;
      int sE4 = s1 & ~3;
      if (sA4 > s1) sA4 = s1;
      if (sE4 < sA4) sE4 = sA4;
      {  // scalar head [s0, sA4)
        int ss = s0 + lane;
        bool pred = (ss < sA4) && (mrow[ss < sA4 ? ss : s0] != 0);
        append(pred, ss);
      }
      for (int s = sA4; s < sE4; s += 256) {
        int idx = s + lane * 4;
        ushort4 m4 = {0, 0, 0, 0};
        if (idx < sE4) m4 = *(const ushort4*)(mrow + idx);
        bool inr = idx < sE4;
        append(inr && m4.x != 0, idx);
        append(inr && m4.y != 0, idx + 1);
        append(inr && m4.z != 0, idx + 2);
        append(inr && m4.w != 0, idx + 3);
      }
      {  // scalar tail [sE4, s1)
        int ss = sE4 + lane;
        bool pred = (ss < s1) && (mrow[ss < s1 ? ss : sE4] != 0);
        append(pred, ss);
      }
    } else {
      for (int s = s0; s < s1; s += 64) {
        int ss = s + lane;
        bool pred = false;
        if (ss < s1) pred = msknzT<DT>(mp, (long)t * mts + (long)ss * mss);
        append(pred, ss);
      }
    }
    if (lane == 0) nnz[bi] = base;
  } else {
    int row = (blockIdx.x - 3840) * 4 + wid;
    int d = (row < 1536) ? 0 : ((row < 4608) ? 1 : 2);
    int r = row - ((d == 0) ? 0 : ((d == 1) ? 1536 : 4608));
    const void* x  = (d == 0) ? x0  : ((d == 1) ? x1  : x2);
    const void* pe = (d == 0) ? pe0 : ((d == 1) ? pe1 : pe2);
    const void* wf = (d == 0) ? wf0 : ((d == 1) ? wf1 : wf2);
    const void* bf = (d == 0) ? bf0 : ((d == 1) ? bf1 : bf2);
    const void* wp = (d == 0) ? wp0 : ((d == 1) ? wp1 : wp2);
    float acc = ldT<DT>(bf, lane);
#pragma unroll 8
    for (int f = 0; f < 32; f++)
      acc += ldT<DT>(x, (long)r * 32 + f) * ldT<DT>(wf, f * 64 + lane);
#pragma unroll 8
    for (int q = 0; q < 16; q++)
      acc += ldT<DT>(pe, (long)r * 16 + q) * ldT<DT>(wp, q * 64 + lane);
    hout[(long)row * 64 + lane] = acc;
  }
}
__global__ void ct67_ellem(const void* adj00, const void* b01, const void* adj11,
                           const void* b12, const void* adj22,
                           const int* bel0, const int* bel1, const int* bel2,
                           int* ranges_ws, int* flags_ws, int* ell, int* nnz, int ellok,
                           const void* x0, const void* pe0, const void* wf0,
                           const void* bf0, const void* wp0, const void* x1,
                           const void* pe1, const void* wf1, const void* bf1,
                           const void* wp1, const void* x2, const void* pe2,
                           const void* wf2, const void* bf2, const void* wp2,
                           float* hout) {
  __shared__ int sR[48];
  __shared__ int sDt;
  int tid = threadIdx.x;
  ct67_selfranges(bel0, bel1, bel2, sR, tid);
  if (tid == 32) sDt = ct67_selfdt((const unsigned short*)x0);
  __syncthreads();
  if (blockIdx.x == 0) {  // persist for downstream kernels
    if (tid < 48) ranges_ws[tid] = sR[tid];
    if (tid == 48) flags_ws[0] = sDt;
  }
  int dt = sDt;
  if (dt == 0)
    ellem_body<0>(adj00,b01,adj11,b12,adj22,bel0,bel1,bel2,sR,ell,nnz,ellok,
                  x0,pe0,wf0,bf0,wp0,x1,pe1,wf1,bf1,wp1,x2,pe2,wf2,bf2,wp2,hout);
  else if (dt == 1)
    ellem_body<1>(adj00,b01,adj11,b12,adj22,bel0,bel1,bel2,sR,ell,nnz,ellok,
                  x0,pe0,wf0,bf0,wp0,x1,pe1,wf1,bf1,wp1,x2,pe2,wf2,bf2,wp2,hout);
  else
    ellem_body<2>(adj00,b01,adj11,b12,adj22,bel0,bel1,bel2,sR,ell,nnz,ellok,
                  x0,pe0,wf0,bf0,wp0,x1,pe1,wf1,bf1,wp1,x2,pe2,wf2,bf2,wp2,hout);
}

// ---------------- kv: 8 rows/block, W decoded once into f32 LDS (k and v only) ----
template <int DT>
__device__ void kv_body(const float* h, const void* Wk, const void* bk,
                        const void* Wv, const void* bv, float* kd, float* vd, int l) {
  const int segendKV[14] = {1536, 3072, 4608, 6144, 9216, 12288, 15360, 18432,
                            21504, 24576, 26112, 27648, 29184, 30720};
  const int sdv[7] = {0, 0, 1, 1, 1, 2, 2};
  const int koff[7] = {0, 1536, 3072, 6144, 9216, 12288, 13824};
  const int rowoff[3] = {0, 1536, 4608};
  __shared__ float sW[4096];
  __shared__ float sh[8][64];
  int tid = threadIdx.x;
  int j = tid % 64;
  int rg = tid / 64;
  int gbase = blockIdx.x * 8;  // all KV segment boundaries are multiples of 8
  int seg = 0;
  while (gbase >= segendKV[seg]) seg++;
  int segstart = (seg == 0) ? 0 : segendKV[seg - 1];
  int i = seg >> 1, role = seg & 1;  // role 0=k, 1=v
  const void* W = role ? Wv : Wk;
  const void* bb = role ? bv : bk;
  long wbase = (long)(l * 7 + i) * 4096;
#pragma unroll
  for (int kkk = 0; kkk < 8; kkk++) {
    int idx = tid + kkk * 512;
    sW[idx] = ldT<DT>(W, wbase + idx);
  }
  int r = gbase - segstart + rg;
  int hrow = rowoff[sdv[i]] + r;
  sh[rg][j] = h[(long)hrow * 64 + j];
  __syncthreads();
  float acc = ldT<DT>(bb, (long)(l * 7 + i) * 64 + j);
#pragma unroll 8
  for (int kk = 0; kk < 64; kk++) acc += sh[rg][kk] * sW[kk * 64 + j];
  float* dst = (role ? vd : kd) + (long)(koff[i] + r) * 64;
  dst[j] = acc;
}
__global__ void ct67_kv(const float* h, const void* Wk, const void* bk,
                        const void* Wv, const void* bv, float* kd, float* vd, int l,
                        const int* dtp) {
  int dt = dtp[0];
  if (dt == 0)      kv_body<0>(h, Wk, bk, Wv, bv, kd, vd, l);
  else if (dt == 1) kv_body<1>(h, Wk, bk, Wv, bv, kd, vd, l);
  else              kv_body<2>(h, Wk, bk, Wv, bv, kd, vd, l);
}

// ---- attention: inline q projection + online softmax + Wo, all-shuffle, no LDS ----
template <int DT>
__device__ void attn_body(const float* h, const void* Wq, const void* bq,
                          const float* kb, const float* vb,
                          const void* Wo, const void* bo,
                          const void* adj00, const void* b01, const void* adj11,
                          const void* b12, const void* adj22,
                          const int* bel0, const int* bel1, const int* bel2,
                          const int* ranges, const int* ell, const int* nnz, int ellok,
                          float* obuf, int l) {
  const int koff[7] = {0, 1536, 3072, 6144, 9216, 12288, 13824};
  const int sdv[7] = {0, 0, 1, 1, 1, 2, 2};
  const int tdv[7] = {0, 1, 0, 1, 2, 1, 2};
  const int rowoff[3] = {0, 1536, 4608};
  int bi = blockIdx.x;
  int i, t;
  ct67_itab(bi, i, t);
  int lane = threadIdx.x;
  int hh = lane / 8, jj = lane % 8;
  // inline q: lane computes q[lane] then redistributes per-head fragments
  int hrow = rowoff[tdv[i]] + t;
  float hown = h[(long)hrow * 64 + lane];
  long wqbase = (long)(l * 7 + i) * 4096;
  float qcol = ldT<DT>(bq, (long)(l * 7 + i) * 64 + lane);
  for (int k = 0; k < 64; k++)
    qcol += __shfl(hown, k, 64) * ldT<DT>(Wq, wqbase + k * 64 + lane);
  float qv[8];
#pragma unroll
  for (int d = 0; d < 8; d++) qv[d] = __shfl(qcol, hh * 8 + d, 64);
  const float* kbase = kb + (long)koff[i] * 64 + hh * 8;
  const float* vbase = vb + (long)koff[i] * 64 + hh * 8;
  float mr = -1e30f, lr = 0.f, o[8];
#pragma unroll
  for (int d = 0; d < 8; d++) o[d] = 0.f;
  int n = ellok ? nnz[bi] : 129;
  if (n <= 128) {
    const int* hl = ell + (long)bi * 128;
    for (int hidx = jj; hidx < n; hidx += 8) {
      int s = hl[hidx];
      const float4* kp = (const float4*)(kbase + (long)s * 64);
      float4 k0 = kp[0], k1 = kp[1];
      float sc = qv[0] * k0.x + qv[1] * k0.y + qv[2] * k0.z + qv[3] * k0.w +
                 qv[4] * k1.x + qv[5] * k1.y + qv[6] * k1.z + qv[7] * k1.w;
      sc *= 0.35355339059327373f;
      float nm = fmaxf(mr, sc);
      float fo = expf(mr - nm);
      float wv = expf(sc - nm);
      lr = lr * fo + wv;
      const float4* vp = (const float4*)(vbase + (long)s * 64);
      float4 v0 = vp[0], v1 = vp[1];
      o[0] = o[0] * fo + wv * v0.x; o[1] = o[1] * fo + wv * v0.y;
      o[2] = o[2] * fo + wv * v0.z; o[3] = o[3] * fo + wv * v0.w;
      o[4] = o[4] * fo + wv * v1.x; o[5] = o[5] * fo + wv * v1.y;
      o[6] = o[6] * fo + wv * v1.z; o[7] = o[7] * fo + wv * v1.w;
      mr = nm;
    }
  } else {  // fallback: in-loop mask scan (overflow rows or no ELL workspace)
    const void* mp; long mts, mss;
    ct67_mask<DT>(i, adj00, b01, adj11, b12, adj22, mp, mts, mss);
    const int* belt = (tdv[i] == 0) ? bel0 : ((tdv[i] == 1) ? bel1 : bel2);
    int b = belt[t];
    if (b < 0) b = 0;
    if (b > 7) b = 7;
    const int* rng = ranges + sdv[i] * 16;
    int s0 = rng[b * 2], s1 = rng[b * 2 + 1];
    for (int s = s0 + jj; s < s1; s += 8) {
      if (msknzT<DT>(mp, (long)t * mts + (long)s * mss)) {
        const float4* kp = (const float4*)(kbase + (long)s * 64);
        float4 k0 = kp[0], k1 = kp[1];
        float sc = qv[0] * k0.x + qv[1] * k0.y + qv[2] * k0.z + qv[3] * k0.w +
                   qv[4] * k1.x + qv[5] * k1.y + qv[6] * k1.z + qv[7] * k1.w;
        sc *= 0.35355339059327373f;
        float nm = fmaxf(mr, sc);
        float fo = expf(mr - nm);
        float wv = expf(sc - nm);
        lr = lr * fo + wv;
        const float4* vp = (const float4*)(vbase + (long)s * 64);
        float4 v0 = vp[0], v1 = vp[1];
        o[0] = o[0] * fo + wv * v0.x; o[1] = o[1] * fo + wv * v0.y;
        o[2] = o[2] * fo + wv * v0.z; o[3] = o[3] * fo + wv * v0.w;
        o[4] = o[4] * fo + wv * v1.x; o[5] = o[5] * fo + wv * v1.y;
        o[6] = o[6] * fo + wv * v1.z; o[7] = o[7] * fo + wv * v1.w;
        mr = nm;
      }
    }
  }
  // merge 8 lanes per head via xor-butterfly
#pragma unroll
  for (int off = 1; off < 8; off <<= 1) {
    float m2 = __shfl_xor(mr, off, 64);
    float l2 = __shfl_xor(lr, off, 64);
    float nm = fmaxf(mr, m2);
    float f1 = expf(mr - nm), f2 = expf(m2 - nm);
    lr = lr * f1 + l2 * f2;
#pragma unroll
    for (int d = 0; d < 8; d++) {
      float o2 = __shfl_xor(o[d], off, 64);
      o[d] = o[d] * f1 + o2 * f2;
    }
    mr = nm;
  }
  float val[8];
#pragma unroll
  for (int d = 0; d < 8; d++) val[d] = (lr > 0.f) ? (o[d] / lr) : 0.f;
  // Wo projection via shuffles
  long wobase = (long)(l * 7 + i) * 4096;
  float acc = ldT<DT>(bo, (long)(l * 7 + i) * 64 + lane);
  for (int g = 0; g < 8; g++) {
#pragma unroll
    for (int e = 0; e < 8; e++) {
      float sv = __shfl(val[e], g * 8, 64);
      acc += sv * ldT<DT>(Wo, wobase + (long)(g * 8 + e) * 64 + lane);
    }
  }
  obuf[(long)bi * 64 + lane] = acc;
}
__global__ void CellularTransformer_67345087201410_kernel(
    const float* h, const void* Wq, const void* bq, const float* kb, const float* vb,
    const void* Wo, const void* bo, const void* adj00, const void* b01,
    const void* adj11, const void* b12, const void* adj22,
    const int* bel0, const int* bel1, const int* bel2,
    const int* ranges, const int* ell, const int* nnz, int ellok,
    float* obuf, int l, const int* dtp) {
  int dt = dtp[0];
  if (dt == 0)
    attn_body<0>(h,Wq,bq,kb,vb,Wo,bo,adj00,b01,adj11,b12,adj22,bel0,bel1,bel2,
                 ranges,ell,nnz,ellok,obuf,l);
  else if (dt == 1)
    attn_body<1>(h,Wq,bq,kb,vb,Wo,bo,adj00,b01,adj11,b12,adj22,bel0,bel1,bel2,
                 ranges,ell,nnz,ellok,obuf,l);
  else
    attn_body<2>(h,Wq,bq,kb,vb,Wo,bo,adj00,b01,adj11,b12,adj22,bel0,bel1,bel2,
                 ranges,ell,nnz,ellok,obuf,l);
}

// ---------------- fused FFN: LN1 -> FF1(relu) -> FF2 -> LN2, all in LDS ----------
template <int DT>
__device__ void ffn_body(const float* h, const float* obuf, float* hout,
                         const void* W1, const void* b1, const void* W2, const void* b2,
                         const void* g1, const void* be1, const void* g2, const void* be2,
                         int l) {
  __shared__ float sh[64];
  __shared__ float sf[256];
  __shared__ float sp[4][64];
  int row = blockIdx.x;
  int tid = threadIdx.x;
  int d = (row < 1536) ? 0 : ((row < 4608) ? 1 : 2);
  long gb = (long)(l * 3 + d) * 64;
  if (tid < 64) {
    int j = tid;
    float x = h[(long)row * 64 + j];
    if (d == 0) {
      int r = row;
      x += obuf[(long)r * 64 + j] + obuf[(long)(4608 + r) * 64 + j];
    } else if (d == 1) {
      int r = row - 1536;
      x += obuf[(long)(1536 + r) * 64 + j] + obuf[(long)(6144 + r) * 64 + j] +
           obuf[(long)(10752 + r) * 64 + j];
    } else {
      int r = row - 4608;
      x += obuf[(long)(9216 + r) * 64 + j] + obuf[(long)(13824 + r) * 64 + j];
    }
    float mu = wred64(x) * 0.015625f;
    float dx = x - mu;
    float var = wred64(dx * dx) * 0.015625f;
    sh[j] = dx * rsqrtf(var + 1e-5f) * ldT<DT>(g1, gb + j) + ldT<DT>(be1, gb + j);
  }
  __syncthreads();
  long wb1 = (long)(l * 3 + d) * 16384;
  float acc = ldT<DT>(b1, (long)(l * 3 + d) * 256 + tid);
#pragma unroll 8
  for (int kk = 0; kk < 64; kk++) acc += sh[kk] * ldT<DT>(W1, wb1 + kk * 256 + tid);
  sf[tid] = fmaxf(acc, 0.f);
  __syncthreads();
  int p = tid >> 6, j = tid & 63;
  long wb2 = (long)(l * 3 + d) * 16384;
  float a2 = 0.f;
  int k0 = p * 64;
#pragma unroll 8
  for (int kk = 0; kk < 64; kk++) a2 += sf[k0 + kk] * ldT<DT>(W2, wb2 + (long)(k0 + kk) * 64 + j);
  sp[p][j] = a2;
  __syncthreads();
  if (tid < 64) {
    float x = sh[tid] + ldT<DT>(b2, gb + tid) +
              sp[0][tid] + sp[1][tid] + sp[2][tid] + sp[3][tid];
    float mu = wred64(x) * 0.015625f;
    float dx = x - mu;
    float var = wred64(dx * dx) * 0.015625f;
    hout[(long)row * 64 + tid] =
        dx * rsqrtf(var + 1e-5f) * ldT<DT>(g2, gb + tid) + ldT<DT>(be2, gb + tid);
  }
}
__global__ void ct67_ffn(const float* h, const float* obuf, float* hout,
                         const void* W1, const void* b1, const void* W2, const void* b2,
                         const void* g1, const void* be1, const void* g2, const void* be2,
                         int l, const int* dtp) {
  int dt = dtp[0];
  if (dt == 0)      ffn_body<0>(h, obuf, hout, W1, b1, W2, b2, g1, be1, g2, be2, l);
  else if (dt == 1) ffn_body<1>(h, obuf, hout, W1, b1, W2, b2, g1, be1, g2, be2, l);
  else              ffn_body<2>(h, obuf, hout, W1, b1, W2, b2, g1, be1, g2, be2, l);
}

// ---------------- pooling stage 1: 256 blocks of partials ----------------
__global__ void ct67_poolp(const float* h, const int* ranges, float* ppart) {
  int b = blockIdx.x;
  int c = blockIdx.y;
  int j = threadIdx.x;
  float s = 0.f;
  for (int d = 0; d < 3; d++) {
    int st = ranges[(d * 8 + b) * 2], en = ranges[(d * 8 + b) * 2 + 1];
    int ro = (d == 0) ? 0 : ((d == 1) ? 1536 : 4608);
    for (int r = st + c; r < en; r += 32) s += h[(long)(ro + r) * 64 + j];
  }
  ppart[(long)(b * 32 + c) * 64 + j] = s;
}

// ---------------- merged pool-final + head MLP (1 block, 512 threads) ----------------
template <int DT>
__device__ void poolmlp_body(const float* ppart, const int* ranges,
                             const void* Wh1, const void* bh1, const void* Wh2,
                             const void* bh2, const void* Wh3, const void* bh3,
                             float* out) {
  __shared__ float pooled[8][64];
  __shared__ float y1[8][64];
  __shared__ float y2[8][64];
  int tid = threadIdx.x;
  int b = tid / 64, j = tid % 64;
  float s = 0.f;
  for (int c = 0; c < 32; c++) s += ppart[(long)(b * 32 + c) * 64 + j];
  int cnt = 0;
  for (int d = 0; d < 3; d++)
    cnt += ranges[(d * 8 + b) * 2 + 1] - ranges[(d * 8 + b) * 2];
  pooled[b][j] = (cnt > 0) ? (s / (float)cnt) : 0.f;
  __syncthreads();
  float acc = ldT<DT>(bh1, j);
  for (int kk = 0; kk < 64; kk++) acc += pooled[b][kk] * ldT<DT>(Wh1, kk * 64 + j);
  y1[b][j] = fmaxf(acc, 0.f);
  __syncthreads();
  acc = ldT<DT>(bh2, j);
  for (int kk = 0; kk < 64; kk++) acc += y1[b][kk] * ldT<DT>(Wh2, kk * 64 + j);
  y2[b][j] = fmaxf(acc, 0.f);
  __syncthreads();
  if (j < 10) {
    float o = ldT<DT>(bh3, j);
    for (int kk = 0; kk < 64; kk++) o += y2[b][kk] * ldT<DT>(Wh3, kk * 10 + j);
    out[b * 10 + j] = o;
  }
}
__global__ void ct67_poolmlp(const float* ppart, const int* ranges,
                             const void* Wh1, const void* bh1, const void* Wh2,
                             const void* bh2, const void* Wh3, const void* bh3,
                             float* out, const int* dtp) {
  int dt = dtp[0];
  if (dt == 0)      poolmlp_body<0>(ppart, ranges, Wh1, bh1, Wh2, bh2, Wh3, bh3, out);
  else if (dt == 1) poolmlp_body<1>(ppart, ranges, Wh1, bh1, Wh2, bh2, Wh3, bh3, out);
  else              poolmlp_body<2>(ppart, ranges, Wh1, bh1, Wh2, bh2, Wh3, bh3, out);
}

extern "C" void kernel_launch(void* const* d_in, const int* in_sizes, int n_in,
                              void* d_out, int out_size, void* d_ws, size_t ws_size,
                              hipStream_t stream) {
  (void)in_sizes; (void)n_in; (void)out_size;
  const void* x0 = d_in[0];  const void* pe0 = d_in[1];  const int* bel0 = (const int*)d_in[2];
  const void* x1 = d_in[3];  const void* pe1 = d_in[4];  const int* bel1 = (const int*)d_in[5];
  const void* x2 = d_in[6];  const void* pe2 = d_in[7];  const int* bel2 = (const int*)d_in[8];
  const void* adj00 = d_in[9];  const void* adj11 = d_in[10]; const void* adj22 = d_in[11];
  const void* b01 = d_in[12];   const void* b12 = d_in[13];
  const void* Wf0 = d_in[14]; const void* bf0 = d_in[15]; const void* Wp0 = d_in[16];
  const void* Wf1 = d_in[17]; const void* bf1 = d_in[18]; const void* Wp1 = d_in[19];
  const void* Wf2 = d_in[20]; const void* bf2 = d_in[21]; const void* Wp2 = d_in[22];
  const void* Wq = d_in[23]; const void* bq = d_in[24];
  const void* Wk = d_in[25]; const void* bk = d_in[26];
  const void* Wv = d_in[27]; const void* bv = d_in[28];
  const void* Wo = d_in[29]; const void* bo = d_in[30];
  const void* g1 = d_in[31]; const void* be1 = d_in[32];
  const void* g2 = d_in[33]; const void* be2 = d_in[34];
  const void* Wff1 = d_in[35]; const void* bff1 = d_in[36];
  const void* Wff2 = d_in[37]; const void* bff2 = d_in[38];
  const void* Wh1 = d_in[39]; const void* bh1 = d_in[40];
  const void* Wh2 = d_in[41]; const void* bh2 = d_in[42];
  const void* Wh3 = d_in[43]; const void* bh3 = d_in[44];

  char* w = (char*)d_ws;
  float* hbuf   = (float*)(w + 0);          // 1572864
  float* obuf   = (float*)(w + 1572864);    // -> 5505024
  float* kb     = (float*)(w + 5505024);    // -> 9437184
  float* vb     = (float*)(w + 9437184);    // -> 13369344
  int* ranges   = (int*)(w + 13369344);     // -> 13369536
  int* flags    = (int*)(w + 13369536);     // -> 13369600
  float* ppart  = (float*)(w + 13369600);   // -> 13435136
  int* ell      = (int*)(w + 13435136);     // -> 21299456
  int* nnz      = (int*)(w + 21299456);     // -> 21360896
  int ellok = (ws_size >= (size_t)21360896) ? 1 : 0;

  ct67_ellem<<<5376, 256, 0, stream>>>(adj00, b01, adj11, b12, adj22,
                                       bel0, bel1, bel2, ranges, flags, ell, nnz, ellok,
                                       x0, pe0, Wf0, bf0, Wp0, x1, pe1, Wf1, bf1, Wp1,
                                       x2, pe2, Wf2, bf2, Wp2, hbuf);
  for (int l = 0; l < 2; l++) {
    ct67_kv<<<3840, 512, 0, stream>>>(hbuf, Wk, bk, Wv, bv, kb, vb, l, flags);
    CellularTransformer_67345087201410_kernel<<<15360, 64, 0, stream>>>(
        hbuf, Wq, bq, kb, vb, Wo, bo, adj00, b01, adj11, b12, adj22,
        bel0, bel1, bel2, ranges, ell, nnz, ellok, obuf, l, flags);
    ct67_ffn<<<6144, 256, 0, stream>>>(hbuf, obuf, hbuf, Wff1, bff1, Wff2, bff2,
                                       g1, be1, g2, be2, l, flags);
  }
  ct67_poolp<<<dim3(8, 32), 64, 0, stream>>>(hbuf, ranges, ppart);
  ct67_poolmlp<<<1, 512, 0, stream>>>(ppart, ranges, Wh1, bh1, Wh2, bh2, Wh3, bh3,
                                      (float*)d_out, flags);
}

// Round 16
// 388.667 us; speedup vs baseline: 1.0312x; 1.0312x over previous
//
#include <hip/hip_runtime.h>
#include <hip/hip_bf16.h>
#include <hip/hip_fp16.h>

// Storage-dtype-templated load: DT=0 bf16, DT=1 fp16, DT=2 f32.
template <int DT>
__device__ __forceinline__ float ldT(const void* p, long i) {
  if (DT == 0) {
    unsigned int a = ((unsigned int)((const unsigned short*)p)[i]) << 16;
    union { unsigned int u; float f; } c; c.u = a; return c.f;
  } else if (DT == 1) {
    return __half2float(((const __half*)p)[i]);
  } else {
    return ((const float*)p)[i];
  }
}
template <int DT>
__device__ __forceinline__ bool msknzT(const void* p, long i) {
  if (DT < 2) return ((const unsigned short*)p)[i] != 0;  // 0.0 encodes as 0x0000
  return ((const float*)p)[i] != 0.f;
}
__device__ __forceinline__ float wred64(float v) {
#pragma unroll
  for (int off = 1; off < 64; off <<= 1) v += __shfl_xor(v, off, 64);
  return v;
}
__device__ __forceinline__ void ct67_itab(int bi, int& i, int& t) {
  const int toff[8] = {0, 1536, 4608, 6144, 9216, 10752, 13824, 15360};
  i = 0;
  while (bi >= toff[i + 1]) i++;
  t = bi - toff[i];
}
template <int DT>
__device__ __forceinline__ void ct67_mask(int i, const void* adj00, const void* b01,
                                          const void* adj11, const void* b12,
                                          const void* adj22, const void*& mp,
                                          long& mts, long& mss) {
  switch (i) {
    case 0: mp = adj00; mts = 1536; mss = 1; break;
    case 1: mp = b01;   mts = 1;    mss = 3072; break;
    case 2: mp = b01;   mts = 3072; mss = 1; break;
    case 3: mp = adj11; mts = 3072; mss = 1; break;
    case 4: mp = b12;   mts = 1;    mss = 1536; break;
    case 5: mp = b12;   mts = 1536; mss = 1; break;
    default: mp = adj22; mts = 1536; mss = 1; break;
  }
}

// ---------------- init: dtype classify + batch ranges ----------------
__global__ void ct67_init(const unsigned short* x0u, const int* b0, const int* b1,
                          const int* b2, int* ranges, int* flags) {
  int t = threadIdx.x;
  if (t == 63) {
    float vals[32], mean = 0.f, var = 0.f;
    for (int i = 0; i < 32; i++) {
      union { unsigned int u; float f; } c;
      c.u = ((unsigned int)x0u[i]) << 16;
      vals[i] = c.f; mean += c.f;
    }
    mean /= 32.f;
    for (int i = 0; i < 32; i++) var += (vals[i] - mean) * (vals[i] - mean);
    var /= 32.f;
    flags[0] = (var < 1e-6f) ? 1 : ((var < 1e3f) ? 0 : 2);
  }
  if (t < 24) {
    int d = t / 8, b = t % 8;
    const int* bel = (d == 0) ? b0 : ((d == 1) ? b1 : b2);
    int N = (d == 1) ? 3072 : 1536;
    int lo = 0, hi = N;
    while (lo < hi) { int m = (lo + hi) / 2; if (bel[m] < b) lo = m + 1; else hi = m; }
    int st = lo; hi = N;
    while (lo < hi) { int m = (lo + hi) / 2; if (bel[m] < b + 1) lo = m + 1; else hi = m; }
    ranges[t * 2] = st;
    ranges[t * 2 + 1] = lo;
  }
}

// ---------------- merged ELL-build + embed (independent stages, one launch) ------
// blocks [0,3840): ELL build, 4 waves x 1 row each. blocks [3840,5376): embed 4 rows.
template <int DT>
__device__ void ellem_body(const void* adj00, const void* b01, const void* adj11,
                           const void* b12, const void* adj22,
                           const int* bel0, const int* bel1, const int* bel2,
                           const int* ranges, int* ell, int* nnz,
                           const void* x0, const void* pe0, const void* wf0,
                           const void* bf0, const void* wp0, const void* x1,
                           const void* pe1, const void* wf1, const void* bf1,
                           const void* wp1, const void* x2, const void* pe2,
                           const void* wf2, const void* bf2, const void* wp2,
                           float* hout) {
  int tid = threadIdx.x;
  int lane = tid % 64, wid = tid / 64;
  if (blockIdx.x < 3840) {
    const int sdv[7] = {0, 0, 1, 1, 1, 2, 2};
    const int tdv[7] = {0, 1, 0, 1, 2, 1, 2};
    int bi = blockIdx.x * 4 + wid;
    int i, t;
    ct67_itab(bi, i, t);
    const void* mp; long mts, mss;
    ct67_mask<DT>(i, adj00, b01, adj11, b12, adj22, mp, mts, mss);
    const int* belt = (tdv[i] == 0) ? bel0 : ((tdv[i] == 1) ? bel1 : bel2);
    int b = belt[t];
    if (b < 0) b = 0;
    if (b > 7) b = 7;
    const int* rng = ranges + sdv[i] * 16;
    int s0 = rng[b * 2], s1 = rng[b * 2 + 1];
    int base = 0;
    for (int s = s0; s < s1; s += 64) {
      int ss = s + lane;
      bool pred = false;
      if (ss < s1) pred = msknzT<DT>(mp, (long)t * mts + (long)ss * mss);
      unsigned long long bal = __ballot(pred);
      int pos = __popcll(bal & ((1ull << lane) - 1ull));
      if (pred && base + pos < 128) ell[(long)bi * 128 + base + pos] = ss;
      base += __popcll(bal);
    }
    if (lane == 0) nnz[bi] = base;
  } else {
    int row = (blockIdx.x - 3840) * 4 + wid;
    int d = (row < 1536) ? 0 : ((row < 4608) ? 1 : 2);
    int r = row - ((d == 0) ? 0 : ((d == 1) ? 1536 : 4608));
    const void* x  = (d == 0) ? x0  : ((d == 1) ? x1  : x2);
    const void* pe = (d == 0) ? pe0 : ((d == 1) ? pe1 : pe2);
    const void* wf = (d == 0) ? wf0 : ((d == 1) ? wf1 : wf2);
    const void* bf = (d == 0) ? bf0 : ((d == 1) ? bf1 : bf2);
    const void* wp = (d == 0) ? wp0 : ((d == 1) ? wp1 : wp2);
    float acc = ldT<DT>(bf, lane);
#pragma unroll 8
    for (int f = 0; f < 32; f++)
      acc += ldT<DT>(x, (long)r * 32 + f) * ldT<DT>(wf, f * 64 + lane);
#pragma unroll 8
    for (int q = 0; q < 16; q++)
      acc += ldT<DT>(pe, (long)r * 16 + q) * ldT<DT>(wp, q * 64 + lane);
    hout[(long)row * 64 + lane] = acc;
  }
}
__global__ void ct67_ellem(const void* adj00, const void* b01, const void* adj11,
                           const void* b12, const void* adj22,
                           const int* bel0, const int* bel1, const int* bel2,
                           const int* ranges, int* ell, int* nnz,
                           const void* x0, const void* pe0, const void* wf0,
                           const void* bf0, const void* wp0, const void* x1,
                           const void* pe1, const void* wf1, const void* bf1,
                           const void* wp1, const void* x2, const void* pe2,
                           const void* wf2, const void* bf2, const void* wp2,
                           float* hout, const int* dtp) {
  int dt = dtp[0];
  if (dt == 0)
    ellem_body<0>(adj00,b01,adj11,b12,adj22,bel0,bel1,bel2,ranges,ell,nnz,
                  x0,pe0,wf0,bf0,wp0,x1,pe1,wf1,bf1,wp1,x2,pe2,wf2,bf2,wp2,hout);
  else if (dt == 1)
    ellem_body<1>(adj00,b01,adj11,b12,adj22,bel0,bel1,bel2,ranges,ell,nnz,
                  x0,pe0,wf0,bf0,wp0,x1,pe1,wf1,bf1,wp1,x2,pe2,wf2,bf2,wp2,hout);
  else
    ellem_body<2>(adj00,b01,adj11,b12,adj22,bel0,bel1,bel2,ranges,ell,nnz,
                  x0,pe0,wf0,bf0,wp0,x1,pe1,wf1,bf1,wp1,x2,pe2,wf2,bf2,wp2,hout);
}

// ---------------- qkv: 8 rows/block, W decoded once into f32 LDS ----------------
template <int DT>
__device__ void qkv_body(const float* h, const void* Wq, const void* bq, const void* Wk,
                         const void* bk, const void* Wv, const void* bv,
                         float* qd, float* kd, float* vd, int l) {
  const int segend[21] = {1536, 3072, 4608, 7680, 9216, 10752, 12288, 15360, 18432,
                          21504, 24576, 27648, 29184, 32256, 35328, 38400, 39936,
                          41472, 43008, 44544, 46080};
  const int segsrc[21] = {0, 0, 0, 1, 0, 0, 0, 1, 1, 1, 1, 1, 2, 1, 1, 1, 2, 2, 2, 2, 2};
  const int segdst[21] = {0, 0, 0, 1536, 1536, 1536, 4608, 3072, 3072, 6144, 6144, 6144,
                          9216, 9216, 9216, 10752, 12288, 12288, 13824, 13824, 13824};
  const int rowoff[3] = {0, 1536, 4608};
  __shared__ float sW[4096];
  __shared__ float sh[8][64];
  int tid = threadIdx.x;
  int j = tid % 64;
  int rg = tid / 64;
  int gbase = blockIdx.x * 8;
  int seg = 0;
  while (gbase >= segend[seg]) seg++;
  int segstart = (seg == 0) ? 0 : segend[seg - 1];
  int i = seg / 3, role = seg - i * 3;
  const void* W = (role == 0) ? Wq : (role == 1) ? Wk : Wv;
  const void* bb = (role == 0) ? bq : (role == 1) ? bk : bv;
  long wbase = (long)(l * 7 + i) * 4096;
#pragma unroll
  for (int kkk = 0; kkk < 8; kkk++) {
    int idx = tid + kkk * 512;
    sW[idx] = ldT<DT>(W, wbase + idx);
  }
  int r = gbase - segstart + rg;
  int hrow = rowoff[segsrc[seg]] + r;
  sh[rg][j] = h[(long)hrow * 64 + j];
  __syncthreads();
  float acc = ldT<DT>(bb, (long)(l * 7 + i) * 64 + j);
#pragma unroll 8
  for (int kk = 0; kk < 64; kk++) acc += sh[rg][kk] * sW[kk * 64 + j];
  float* dst = ((role == 0) ? qd : (role == 1) ? kd : vd) + (long)(segdst[seg] + r) * 64;
  dst[j] = acc;
}
__global__ void ct67_qkv(const float* h, const void* Wq, const void* bq, const void* Wk,
                         const void* bk, const void* Wv, const void* bv,
                         float* qd, float* kd, float* vd, int l, const int* dtp) {
  int dt = dtp[0];
  if (dt == 0)      qkv_body<0>(h, Wq, bq, Wk, bk, Wv, bv, qd, kd, vd, l);
  else if (dt == 1) qkv_body<1>(h, Wq, bq, Wk, bk, Wv, bv, qd, kd, vd, l);
  else              qkv_body<2>(h, Wq, bq, Wk, bk, Wv, bv, qd, kd, vd, l);
}

// ---------------- attention + output projection: all-shuffle, no LDS/barriers ----
template <int DT>
__device__ void attn_body(const float* qb, const float* kb, const float* vb,
                          const void* Wo, const void* bo,
                          const void* adj00, const void* b01, const void* adj11,
                          const void* b12, const void* adj22,
                          const int* bel0, const int* bel1, const int* bel2,
                          const int* ranges, const int* ell, const int* nnz, int ellok,
                          float* obuf, int l) {
  const int koff[7] = {0, 1536, 3072, 6144, 9216, 12288, 13824};
  const int sdv[7] = {0, 0, 1, 1, 1, 2, 2};
  const int tdv[7] = {0, 1, 0, 1, 2, 1, 2};
  int bi = blockIdx.x;
  int i, t;
  ct67_itab(bi, i, t);
  int lane = threadIdx.x;
  int hh = lane / 8, jj = lane % 8;
  const float4* qp = (const float4*)(qb + (long)bi * 64 + hh * 8);
  float4 q0 = qp[0], q1 = qp[1];
  const float* kbase = kb + (long)koff[i] * 64 + hh * 8;
  const float* vbase = vb + (long)koff[i] * 64 + hh * 8;
  float mr = -1e30f, lr = 0.f, o[8];
#pragma unroll
  for (int d = 0; d < 8; d++) o[d] = 0.f;
  int n = ellok ? nnz[bi] : 129;
  if (n <= 128) {
    const int* hl = ell + (long)bi * 128;
    for (int hidx = jj; hidx < n; hidx += 8) {
      int s = hl[hidx];
      const float4* kp = (const float4*)(kbase + (long)s * 64);
      float4 k0 = kp[0], k1 = kp[1];
      float sc = q0.x * k0.x + q0.y * k0.y + q0.z * k0.z + q0.w * k0.w +
                 q1.x * k1.x + q1.y * k1.y + q1.z * k1.z + q1.w * k1.w;
      sc *= 0.35355339059327373f;
      float nm = fmaxf(mr, sc);
      float fo = expf(mr - nm);
      float wv = expf(sc - nm);
      lr = lr * fo + wv;
      const float4* vp = (const float4*)(vbase + (long)s * 64);
      float4 v0 = vp[0], v1 = vp[1];
      o[0] = o[0] * fo + wv * v0.x; o[1] = o[1] * fo + wv * v0.y;
      o[2] = o[2] * fo + wv * v0.z; o[3] = o[3] * fo + wv * v0.w;
      o[4] = o[4] * fo + wv * v1.x; o[5] = o[5] * fo + wv * v1.y;
      o[6] = o[6] * fo + wv * v1.z; o[7] = o[7] * fo + wv * v1.w;
      mr = nm;
    }
  } else {  // fallback: in-loop mask scan (overflow rows or no ELL workspace)
    const void* mp; long mts, mss;
    ct67_mask<DT>(i, adj00, b01, adj11, b12, adj22, mp, mts, mss);
    const int* belt = (tdv[i] == 0) ? bel0 : ((tdv[i] == 1) ? bel1 : bel2);
    int b = belt[t];
    if (b < 0) b = 0;
    if (b > 7) b = 7;
    const int* rng = ranges + sdv[i] * 16;
    int s0 = rng[b * 2], s1 = rng[b * 2 + 1];
    for (int s = s0 + jj; s < s1; s += 8) {
      if (msknzT<DT>(mp, (long)t * mts + (long)s * mss)) {
        const float4* kp = (const float4*)(kbase + (long)s * 64);
        float4 k0 = kp[0], k1 = kp[1];
        float sc = q0.x * k0.x + q0.y * k0.y + q0.z * k0.z + q0.w * k0.w +
                   q1.x * k1.x + q1.y * k1.y + q1.z * k1.z + q1.w * k1.w;
        sc *= 0.35355339059327373f;
        float nm = fmaxf(mr, sc);
        float fo = expf(mr - nm);
        float wv = expf(sc - nm);
        lr = lr * fo + wv;
        const float4* vp = (const float4*)(vbase + (long)s * 64);
        float4 v0 = vp[0], v1 = vp[1];
        o[0] = o[0] * fo + wv * v0.x; o[1] = o[1] * fo + wv * v0.y;
        o[2] = o[2] * fo + wv * v0.z; o[3] = o[3] * fo + wv * v0.w;
        o[4] = o[4] * fo + wv * v1.x; o[5] = o[5] * fo + wv * v1.y;
        o[6] = o[6] * fo + wv * v1.z; o[7] = o[7] * fo + wv * v1.w;
        mr = nm;
      }
    }
  }
  // merge 8 lanes per head via xor-butterfly (verified r13)
#pragma unroll
  for (int off = 1; off < 8; off <<= 1) {
    float m2 = __shfl_xor(mr, off, 64);
    float l2 = __shfl_xor(lr, off, 64);
    float nm = fmaxf(mr, m2);
    float f1 = expf(mr - nm), f2 = expf(m2 - nm);
    lr = lr * f1 + l2 * f2;
#pragma unroll
    for (int d = 0; d < 8; d++) {
      float o2 = __shfl_xor(o[d], off, 64);
      o[d] = o[d] * f1 + o2 * f2;
    }
    mr = nm;
  }
  float val[8];
#pragma unroll
  for (int d = 0; d < 8; d++) val[d] = (lr > 0.f) ? (o[d] / lr) : 0.f;
  // Wo projection: broadcast attn output via shuffles (no LDS, no barrier)
  long wobase = (long)(l * 7 + i) * 4096;
  float acc = ldT<DT>(bo, (long)(l * 7 + i) * 64 + lane);
  for (int g = 0; g < 8; g++) {
#pragma unroll
    for (int e = 0; e < 8; e++) {
      float sv = __shfl(val[e], g * 8, 64);
      acc += sv * ldT<DT>(Wo, wobase + (long)(g * 8 + e) * 64 + lane);
    }
  }
  obuf[(long)bi * 64 + lane] = acc;
}
__global__ void CellularTransformer_67345087201410_kernel(
    const float* qb, const float* kb, const float* vb, const void* Wo, const void* bo,
    const void* adj00, const void* b01, const void* adj11, const void* b12,
    const void* adj22, const int* bel0, const int* bel1, const int* bel2,
    const int* ranges, const int* ell, const int* nnz, int ellok,
    float* obuf, int l, const int* dtp) {
  int dt = dtp[0];
  if (dt == 0)
    attn_body<0>(qb,kb,vb,Wo,bo,adj00,b01,adj11,b12,adj22,bel0,bel1,bel2,ranges,ell,nnz,ellok,obuf,l);
  else if (dt == 1)
    attn_body<1>(qb,kb,vb,Wo,bo,adj00,b01,adj11,b12,adj22,bel0,bel1,bel2,ranges,ell,nnz,ellok,obuf,l);
  else
    attn_body<2>(qb,kb,vb,Wo,bo,adj00,b01,adj11,b12,adj22,bel0,bel1,bel2,ranges,ell,nnz,ellok,obuf,l);
}

// ---------------- fused FFN: LN1 -> FF1(relu) -> FF2 -> LN2, all in LDS ----------
template <int DT>
__device__ void ffn_body(const float* h, const float* obuf, float* hout,
                         const void* W1, const void* b1, const void* W2, const void* b2,
                         const void* g1, const void* be1, const void* g2, const void* be2,
                         int l) {
  __shared__ float sh[64];
  __shared__ float sf[256];
  __shared__ float sp[4][64];
  int row = blockIdx.x;
  int tid = threadIdx.x;
  int d = (row < 1536) ? 0 : ((row < 4608) ? 1 : 2);
  long gb = (long)(l * 3 + d) * 64;
  if (tid < 64) {
    int j = tid;
    float x = h[(long)row * 64 + j];
    if (d == 0) {
      int r = row;
      x += obuf[(long)r * 64 + j] + obuf[(long)(4608 + r) * 64 + j];
    } else if (d == 1) {
      int r = row - 1536;
      x += obuf[(long)(1536 + r) * 64 + j] + obuf[(long)(6144 + r) * 64 + j] +
           obuf[(long)(10752 + r) * 64 + j];
    } else {
      int r = row - 4608;
      x += obuf[(long)(9216 + r) * 64 + j] + obuf[(long)(13824 + r) * 64 + j];
    }
    float mu = wred64(x) * 0.015625f;
    float dx = x - mu;
    float var = wred64(dx * dx) * 0.015625f;
    sh[j] = dx * rsqrtf(var + 1e-5f) * ldT<DT>(g1, gb + j) + ldT<DT>(be1, gb + j);
  }
  __syncthreads();
  long wb1 = (long)(l * 3 + d) * 16384;
  float acc = ldT<DT>(b1, (long)(l * 3 + d) * 256 + tid);
#pragma unroll 8
  for (int kk = 0; kk < 64; kk++) acc += sh[kk] * ldT<DT>(W1, wb1 + kk * 256 + tid);
  sf[tid] = fmaxf(acc, 0.f);
  __syncthreads();
  int p = tid >> 6, j = tid & 63;
  long wb2 = (long)(l * 3 + d) * 16384;
  float a2 = 0.f;
  int k0 = p * 64;
#pragma unroll 8
  for (int kk = 0; kk < 64; kk++) a2 += sf[k0 + kk] * ldT<DT>(W2, wb2 + (long)(k0 + kk) * 64 + j);
  sp[p][j] = a2;
  __syncthreads();
  if (tid < 64) {
    float x = sh[tid] + ldT<DT>(b2, gb + tid) +
              sp[0][tid] + sp[1][tid] + sp[2][tid] + sp[3][tid];
    float mu = wred64(x) * 0.015625f;
    float dx = x - mu;
    float var = wred64(dx * dx) * 0.015625f;
    hout[(long)row * 64 + tid] =
        dx * rsqrtf(var + 1e-5f) * ldT<DT>(g2, gb + tid) + ldT<DT>(be2, gb + tid);
  }
}
__global__ void ct67_ffn(const float* h, const float* obuf, float* hout,
                         const void* W1, const void* b1, const void* W2, const void* b2,
                         const void* g1, const void* be1, const void* g2, const void* be2,
                         int l, const int* dtp) {
  int dt = dtp[0];
  if (dt == 0)      ffn_body<0>(h, obuf, hout, W1, b1, W2, b2, g1, be1, g2, be2, l);
  else if (dt == 1) ffn_body<1>(h, obuf, hout, W1, b1, W2, b2, g1, be1, g2, be2, l);
  else              ffn_body<2>(h, obuf, hout, W1, b1, W2, b2, g1, be1, g2, be2, l);
}

// ---------------- pooling stage 1: 256 blocks of partials ----------------
__global__ void ct67_poolp(const float* h, const int* ranges, float* ppart) {
  int b = blockIdx.x;
  int c = blockIdx.y;
  int j = threadIdx.x;
  float s = 0.f;
  for (int d = 0; d < 3; d++) {
    int st = ranges[(d * 8 + b) * 2], en = ranges[(d * 8 + b) * 2 + 1];
    int ro = (d == 0) ? 0 : ((d == 1) ? 1536 : 4608);
    for (int r = st + c; r < en; r += 32) s += h[(long)(ro + r) * 64 + j];
  }
  ppart[(long)(b * 32 + c) * 64 + j] = s;
}

// ---------------- merged pool-final + head MLP (1 block, 512 threads) ----------------
template <int DT>
__device__ void poolmlp_body(const float* ppart, const int* ranges,
                             const void* Wh1, const void* bh1, const void* Wh2,
                             const void* bh2, const void* Wh3, const void* bh3,
                             float* out) {
  __shared__ float pooled[8][64];
  __shared__ float y1[8][64];
  __shared__ float y2[8][64];
  int tid = threadIdx.x;
  int b = tid / 64, j = tid % 64;
  float s = 0.f;
  for (int c = 0; c < 32; c++) s += ppart[(long)(b * 32 + c) * 64 + j];
  int cnt = 0;
  for (int d = 0; d < 3; d++)
    cnt += ranges[(d * 8 + b) * 2 + 1] - ranges[(d * 8 + b) * 2];
  pooled[b][j] = (cnt > 0) ? (s / (float)cnt) : 0.f;
  __syncthreads();
  float acc = ldT<DT>(bh1, j);
  for (int kk = 0; kk < 64; kk++) acc += pooled[b][kk] * ldT<DT>(Wh1, kk * 64 + j);
  y1[b][j] = fmaxf(acc, 0.f);
  __syncthreads();
  acc = ldT<DT>(bh2, j);
  for (int kk = 0; kk < 64; kk++) acc += y1[b][kk] * ldT<DT>(Wh2, kk * 64 + j);
  y2[b][j] = fmaxf(acc, 0.f);
  __syncthreads();
  if (j < 10) {
    float o = ldT<DT>(bh3, j);
    for (int kk = 0; kk < 64; kk++) o += y2[b][kk] * ldT<DT>(Wh3, kk * 10 + j);
    out[b * 10 + j] = o;
  }
}
__global__ void ct67_poolmlp(const float* ppart, const int* ranges,
                             const void* Wh1, const void* bh1, const void* Wh2,
                             const void* bh2, const void* Wh3, const void* bh3,
                             float* out, const int* dtp) {
  int dt = dtp[0];
  if (dt == 0)      poolmlp_body<0>(ppart, ranges, Wh1, bh1, Wh2, bh2, Wh3, bh3, out);
  else if (dt == 1) poolmlp_body<1>(ppart, ranges, Wh1, bh1, Wh2, bh2, Wh3, bh3, out);
  else              poolmlp_body<2>(ppart, ranges, Wh1, bh1, Wh2, bh2, Wh3, bh3, out);
}

extern "C" void kernel_launch(void* const* d_in, const int* in_sizes, int n_in,
                              void* d_out, int out_size, void* d_ws, size_t ws_size,
                              hipStream_t stream) {
  (void)in_sizes; (void)n_in; (void)out_size;
  const void* x0 = d_in[0];  const void* pe0 = d_in[1];  const int* bel0 = (const int*)d_in[2];
  const void* x1 = d_in[3];  const void* pe1 = d_in[4];  const int* bel1 = (const int*)d_in[5];
  const void* x2 = d_in[6];  const void* pe2 = d_in[7];  const int* bel2 = (const int*)d_in[8];
  const void* adj00 = d_in[9];  const void* adj11 = d_in[10]; const void* adj22 = d_in[11];
  const void* b01 = d_in[12];   const void* b12 = d_in[13];
  const void* Wf0 = d_in[14]; const void* bf0 = d_in[15]; const void* Wp0 = d_in[16];
  const void* Wf1 = d_in[17]; const void* bf1 = d_in[18]; const void* Wp1 = d_in[19];
  const void* Wf2 = d_in[20]; const void* bf2 = d_in[21]; const void* Wp2 = d_in[22];
  const void* Wq = d_in[23]; const void* bq = d_in[24];
  const void* Wk = d_in[25]; const void* bk = d_in[26];
  const void* Wv = d_in[27]; const void* bv = d_in[28];
  const void* Wo = d_in[29]; const void* bo = d_in[30];
  const void* g1 = d_in[31]; const void* be1 = d_in[32];
  const void* g2 = d_in[33]; const void* be2 = d_in[34];
  const void* Wff1 = d_in[35]; const void* bff1 = d_in[36];
  const void* Wff2 = d_in[37]; const void* bff2 = d_in[38];
  const void* Wh1 = d_in[39]; const void* bh1 = d_in[40];
  const void* Wh2 = d_in[41]; const void* bh2 = d_in[42];
  const void* Wh3 = d_in[43]; const void* bh3 = d_in[44];

  char* w = (char*)d_ws;
  float* hbuf   = (float*)(w + 0);          // 1572864
  float* obuf   = (float*)(w + 1572864);    // -> 5505024
  float* qb     = (float*)(w + 5505024);    // -> 9437184
  float* kb     = (float*)(w + 9437184);    // -> 13369344
  float* vb     = (float*)(w + 13369344);   // -> 17301504
  int* ranges   = (int*)(w + 17301504);     // -> 17301696
  int* flags    = (int*)(w + 17301696);     // -> 17301760
  float* ppart  = (float*)(w + 17301760);   // -> 17367296
  int* ell      = (int*)(w + 17367296);     // -> 25231616
  int* nnz      = (int*)(w + 25231616);     // -> 25293056
  int ellok = (ws_size >= (size_t)25293056) ? 1 : 0;

  ct67_init<<<1, 64, 0, stream>>>((const unsigned short*)x0, bel0, bel1, bel2, ranges, flags);
  ct67_ellem<<<5376, 256, 0, stream>>>(adj00, b01, adj11, b12, adj22,
                                       bel0, bel1, bel2, ranges, ell, nnz,
                                       x0, pe0, Wf0, bf0, Wp0, x1, pe1, Wf1, bf1, Wp1,
                                       x2, pe2, Wf2, bf2, Wp2, hbuf, flags);
  for (int l = 0; l < 2; l++) {
    ct67_qkv<<<5760, 512, 0, stream>>>(hbuf, Wq, bq, Wk, bk, Wv, bv, qb, kb, vb, l, flags);
    CellularTransformer_67345087201410_kernel<<<15360, 64, 0, stream>>>(
        qb, kb, vb, Wo, bo, adj00, b01, adj11, b12, adj22,
        bel0, bel1, bel2, ranges, ell, nnz, ellok, obuf, l, flags);
    ct67_ffn<<<6144, 256, 0, stream>>>(hbuf, obuf, hbuf, Wff1, bff1, Wff2, bff2,
                                       g1, be1, g2, be2, l, flags);
  }
  ct67_poolp<<<dim3(8, 32), 64, 0, stream>>>(hbuf, ranges, ppart);
  ct67_poolmlp<<<1, 512, 0, stream>>>(ppart, ranges, Wh1, bh1, Wh2, bh2, Wh3, bh3,
                                      (float*)d_out, flags);
}